// Round 1
// baseline (296.109 us; speedup 1.0000x reference)
//
#include <hip/hip_runtime.h>

#define NN 4096
#define FIN 128
#define NHEAD 4
#define NHID 16
#define NCOL 64
#define SLOPE 0.2f

__device__ __forceinline__ float lrelu(float v){ return v > 0.f ? v : SLOPE * v; }

// h = x @ W  (4096x128 @ 128x64)
__global__ __launch_bounds__(256) void gemm_h_k(const float* __restrict__ x,
                                                const float* __restrict__ W,
                                                float* __restrict__ h){
  __shared__ float wl[FIN][NCOL];   // 32 KB
  __shared__ float xl[16][FIN];     // 8 KB
  int t = threadIdx.x;
  for (int k = t; k < FIN * NCOL; k += 256) wl[k >> 6][k & 63] = W[k];
  int row0 = blockIdx.x * 16;
  for (int k = t; k < 16 * FIN; k += 256) xl[k >> 7][k & 127] = x[row0 * FIN + k];
  __syncthreads();
  int col = t & 63;
  int rb  = t >> 6;
  #pragma unroll
  for (int rr = 0; rr < 4; ++rr){
    int r = rb * 4 + rr;
    float acc = 0.f;
    #pragma unroll
    for (int d = 0; d < FIN; ++d) acc = fmaf(xl[r][d], wl[d][col], acc);
    h[(row0 + r) * NCOL + col] = acc;
  }
}

// src[h][n], dst[h][n]
__global__ __launch_bounds__(256) void src_dst_k(const float* __restrict__ h,
                                                 const float* __restrict__ aw,
                                                 float* __restrict__ src,
                                                 float* __restrict__ dst){
  int idx = blockIdx.x * 256 + threadIdx.x;   // n*4 + head
  int n = idx >> 2, hd = idx & 3;
  const float* hp = h + n * NCOL + hd * NHID;
  float s = 0.f, d = 0.f;
  #pragma unroll
  for (int f = 0; f < NHID; ++f){
    float v = hp[f];
    s = fmaf(v, aw[f], s);
    d = fmaf(v, aw[NHID + f], d);
  }
  src[hd * NN + n] = s;
  dst[hd * NN + n] = d;
}

// per-head max of dst
__global__ __launch_bounds__(256) void maxd_k(const float* __restrict__ dst,
                                              float* __restrict__ maxd){
  int hd = blockIdx.x;
  int t = threadIdx.x;
  float m = -1e30f;
  for (int j = t; j < NN; j += 256) m = fmaxf(m, dst[hd * NN + j]);
  #pragma unroll
  for (int o = 32; o; o >>= 1) m = fmaxf(m, __shfl_down(m, o));
  __shared__ float red[4];
  if ((t & 63) == 0) red[t >> 6] = m;
  __syncthreads();
  if (t == 0){
    m = fmaxf(fmaxf(red[0], red[1]), fmaxf(red[2], red[3]));
    maxd[hd] = m;
  }
}

// attention partial sums over a j-chunk; atomicAdd into acc[(hd*NN+i)*17 + {0..15,den}]
__global__ __launch_bounds__(256) void attn_k(const float* __restrict__ h,
                                              const float* __restrict__ src,
                                              const float* __restrict__ dst,
                                              const float* __restrict__ maxd,
                                              float* __restrict__ acc){
  const int TJ  = 128;
  const int JCH = 256;   // 4096 / gridDim.z(16)
  int i  = blockIdx.x * 256 + threadIdx.x;
  int hd = blockIdx.y;
  int j0 = blockIdx.z * JCH;
  float s = src[hd * NN + i];
  float m = lrelu(s + maxd[hd]);
  float a[NHID];
  #pragma unroll
  for (int f = 0; f < NHID; ++f) a[f] = 0.f;
  float den = 0.f;

  __shared__ float dl[TJ];
  __shared__ float hl[TJ][NHID];   // 8 KB

  for (int jt = j0; jt < j0 + JCH; jt += TJ){
    __syncthreads();
    if (threadIdx.x < TJ) dl[threadIdx.x] = dst[hd * NN + jt + threadIdx.x];
    for (int k = threadIdx.x; k < TJ * NHID; k += 256){
      int jj = k >> 4, f = k & 15;
      hl[jj][f] = h[(jt + jj) * NCOL + hd * NHID + f];
    }
    __syncthreads();
    #pragma unroll 4
    for (int jj = 0; jj < TJ; ++jj){
      float w = __expf(lrelu(s + dl[jj]) - m);
      den += w;
      #pragma unroll
      for (int f = 0; f < NHID; ++f) a[f] = fmaf(w, hl[jj][f], a[f]);
    }
  }

  float* ap = acc + (hd * NN + i) * 17;
  #pragma unroll
  for (int f = 0; f < NHID; ++f) atomicAdd(ap + f, a[f]);
  atomicAdd(ap + 16, den);
}

__global__ __launch_bounds__(256) void fin_k(const float* __restrict__ acc,
                                             float* __restrict__ out){
  int idx = blockIdx.x * 256 + threadIdx.x;  // NN*NCOL
  int i = idx >> 6, c = idx & 63;
  int hd = c >> 4, f = c & 15;
  const float* ap = acc + (hd * NN + i) * 17;
  out[idx] = ap[f] / ap[16];
}

extern "C" void kernel_launch(void* const* d_in, const int* in_sizes, int n_in,
                              void* d_out, int out_size, void* d_ws, size_t ws_size,
                              hipStream_t stream){
  const float* x  = (const float*)d_in[0];
  // d_in[1] = adj : UNUSED by the reference (no masking) — never read it.
  const float* W  = (const float*)d_in[2];
  const float* aw = (const float*)d_in[3];
  float* out = (float*)d_out;
  float* ws  = (float*)d_ws;

  float* h    = ws;              // 262144 floats
  float* src  = ws + 262144;     // 16384
  float* dst  = ws + 278528;     // 16384
  float* maxd = ws + 294912;     // 4 (+pad)
  float* acc  = ws + 294976;     // 4096*4*17 = 278528 floats

  hipMemsetAsync(acc, 0, 278528 * sizeof(float), stream);
  gemm_h_k<<<256, 256, 0, stream>>>(x, W, h);
  src_dst_k<<<64, 256, 0, stream>>>(h, aw, src, dst);
  maxd_k<<<4, 256, 0, stream>>>(dst, maxd);
  attn_k<<<dim3(16, 4, 16), 256, 0, stream>>>(h, src, dst, maxd, acc);
  fin_k<<<1024, 256, 0, stream>>>(acc, out);
}

// Round 2
// 235.260 us; speedup vs baseline: 1.2586x; 1.2586x over previous
//
#include <hip/hip_runtime.h>

#define NN 4096
#define FIN 128
#define NHEAD 4
#define NHID 16
#define NCOL 64
#define SLOPE 0.2f
#define KP 4097   // P/S per-column stride (4096 ranks + tail)

__device__ __forceinline__ float lrelu(float v){ return v > 0.f ? v : SLOPE * v; }

// h = x @ W  (4096x128 @ 128x64)
__global__ __launch_bounds__(256) void gemm_h_k(const float* __restrict__ x,
                                                const float* __restrict__ W,
                                                float* __restrict__ h){
  __shared__ float wl[FIN][NCOL];   // 32 KB
  __shared__ float xl[16][FIN];     // 8 KB
  int t = threadIdx.x;
  for (int k = t; k < FIN * NCOL; k += 256) wl[k >> 6][k & 63] = W[k];
  int row0 = blockIdx.x * 16;
  for (int k = t; k < 16 * FIN; k += 256) xl[k >> 7][k & 127] = x[row0 * FIN + k];
  __syncthreads();
  int col = t & 63;
  int rb  = t >> 6;
  #pragma unroll
  for (int rr = 0; rr < 4; ++rr){
    int r = rb * 4 + rr;
    float acc = 0.f;
    #pragma unroll
    for (int d = 0; d < FIN; ++d) acc = fmaf(xl[r][d], wl[d][col], acc);
    h[(row0 + r) * NCOL + col] = acc;
  }
}

// src[h][n], dst[h][n]
__global__ __launch_bounds__(256) void src_dst_k(const float* __restrict__ h,
                                                 const float* __restrict__ aw,
                                                 float* __restrict__ src,
                                                 float* __restrict__ dst){
  int idx = blockIdx.x * 256 + threadIdx.x;   // n*4 + head
  int n = idx >> 2, hd = idx & 3;
  const float* hp = h + n * NCOL + hd * NHID;
  float s = 0.f, d = 0.f;
  #pragma unroll
  for (int f = 0; f < NHID; ++f){
    float v = hp[f];
    s = fmaf(v, aw[f], s);
    d = fmaf(v, aw[NHID + f], d);
  }
  src[hd * NN + n] = s;
  dst[hd * NN + n] = d;
}

// per-head ascending bitonic sort of dst, carrying original index
__global__ __launch_bounds__(1024) void sort_k(const float* __restrict__ dst,
                                               float* __restrict__ dsort,
                                               int* __restrict__ perm){
  int hd = blockIdx.x;
  __shared__ float v[NN];
  __shared__ int  ix[NN];
  int t = threadIdx.x;
  for (int k = t; k < NN; k += 1024){ v[k] = dst[hd * NN + k]; ix[k] = k; }
  __syncthreads();
  for (int kk = 2; kk <= NN; kk <<= 1){
    for (int j = kk >> 1; j > 0; j >>= 1){
      for (int q = t; q < NN / 2; q += 1024){
        int i = ((q & ~(j - 1)) << 1) | (q & (j - 1));
        int p = i | j;
        bool up = ((i & kk) == 0);
        float a = v[i], b = v[p];
        bool sw = up ? (a > b) : (a < b);
        if (sw){
          v[i] = b; v[p] = a;
          int tmp = ix[i]; ix[i] = ix[p]; ix[p] = tmp;
        }
      }
      __syncthreads();
    }
  }
  for (int k = t; k < NN; k += 1024){
    dsort[hd * NN + k] = v[k];
    perm[hd * NN + k]  = ix[k];
  }
}

// P[hd][c][k] = sum_{r<k} e^{0.2 d_r} * v_c(perm[r])   (exclusive prefix)
// S[hd][c][k] = sum_{r>=k} e^{d_r}   * v_c(perm[r])   (inclusive suffix)
// c in [0,16]: c<16 -> h[perm][hd*16+c], c==16 -> 1 (denominator column)
__global__ __launch_bounds__(1024) void prefix_k(const float* __restrict__ h,
                                                 const float* __restrict__ dsort,
                                                 const int* __restrict__ perm,
                                                 float* __restrict__ P,
                                                 float* __restrict__ S){
  int hd = blockIdx.x;
  int t = threadIdx.x;
  __shared__ float e02[NN], e1[NN];          // 32 KB
  __shared__ float csumP[32][17], csumS[32][17];
  __shared__ float coffP[32][17], coffS[32][17];
  const float* ds = dsort + hd * NN;
  const int*   pm = perm + hd * NN;
  for (int k = t; k < NN; k += 1024){
    float d = ds[k];
    e02[k] = __expf(0.2f * d);
    e1[k]  = __expf(d);
  }
  __syncthreads();
  int chunk = t / 17, col = t % 17;          // 32 chunks x 17 cols = 544 workers
  if (t < 544){
    int base = chunk * 128;
    float sp = 0.f, ss = 0.f;
    #pragma unroll 4
    for (int r = 0; r < 128; ++r){
      int k = base + r;
      float vv = (col < 16) ? h[pm[k] * NCOL + hd * NHID + col] : 1.0f;
      sp = fmaf(e02[k], vv, sp);
      ss = fmaf(e1[k],  vv, ss);
    }
    csumP[chunk][col] = sp;
    csumS[chunk][col] = ss;
  }
  __syncthreads();
  if (t < 17){
    float run = 0.f;
    for (int c = 0; c < 32; ++c){ coffP[c][t] = run; run += csumP[c][t]; }
    // tails: P[...][4096] = total prefix, S[...][4096] = 0
    P[(hd * 17 + t) * KP + NN] = run;
    S[(hd * 17 + t) * KP + NN] = 0.f;
    float rs = 0.f;
    for (int c = 31; c >= 0; --c){ coffS[c][t] = rs; rs += csumS[c][t]; }
  }
  __syncthreads();
  if (t < 544){
    int base = chunk * 128;
    float* Pp = P + (hd * 17 + col) * KP;
    float* Sp = S + (hd * 17 + col) * KP;
    float run = coffP[chunk][col];
    #pragma unroll 4
    for (int r = 0; r < 128; ++r){
      int k = base + r;
      float vv = (col < 16) ? h[pm[k] * NCOL + hd * NHID + col] : 1.0f;
      Pp[k] = run;
      run = fmaf(e02[k], vv, run);
    }
    float rs = coffS[chunk][col];
    #pragma unroll 4
    for (int r = 127; r >= 0; --r){
      int k = base + r;
      float vv = (col < 16) ? h[pm[k] * NCOL + hd * NHID + col] : 1.0f;
      rs = fmaf(e1[k], vv, rs);
      Sp[k] = rs;
    }
  }
}

// per (i, head): binary search kink, combine prefix/suffix
__global__ __launch_bounds__(256) void out_k(const float* __restrict__ src,
                                             const float* __restrict__ dsort,
                                             const float* __restrict__ P,
                                             const float* __restrict__ S,
                                             float* __restrict__ out){
  int idx = blockIdx.x * 256 + threadIdx.x;  // 16384 = NN*NHEAD
  int i = idx >> 2, hd = idx & 3;
  float s = src[hd * NN + i];
  const float* ds = dsort + hd * NN;
  float m = lrelu(s + ds[NN - 1]);           // max_j e_ij (monotone lrelu)
  float tthr = -s;
  int lo = 0, hi = NN;
  while (lo < hi){
    int mid = (lo + hi) >> 1;
    if (ds[mid] < tthr) lo = mid + 1; else hi = mid;
  }
  int k = lo;                                 // ranks < k are in the 0.2-branch
  float alpha = __expf(0.2f * s - m);
  float beta  = __expf(s - m);
  const float* Pp = P + hd * 17 * KP + k;
  const float* Sp = S + hd * 17 * KP + k;
  float den = fmaf(alpha, Pp[16 * KP], beta * Sp[16 * KP]);
  float inv = 1.0f / den;
  #pragma unroll
  for (int f = 0; f < 16; ++f){
    float num = fmaf(alpha, Pp[f * KP], beta * Sp[f * KP]);
    out[i * NCOL + hd * NHID + f] = num * inv;
  }
}

extern "C" void kernel_launch(void* const* d_in, const int* in_sizes, int n_in,
                              void* d_out, int out_size, void* d_ws, size_t ws_size,
                              hipStream_t stream){
  const float* x  = (const float*)d_in[0];
  // d_in[1] = adj : UNUSED by the reference (no masking) — never read it.
  const float* W  = (const float*)d_in[2];
  const float* aw = (const float*)d_in[3];
  float* out = (float*)d_out;
  float* ws  = (float*)d_ws;

  float* h     = ws;                // 262144
  float* src   = ws + 262144;       // 16384
  float* dst   = ws + 278528;       // 16384
  float* dsort = ws + 294912;       // 16384
  int*   perm  = (int*)(ws + 311296); // 16384
  float* P     = ws + 327680;       // 4*17*KP = 278596
  float* S     = ws + 606276;       // 278596
  // total 884872 floats = 3.54 MB

  gemm_h_k<<<256, 256, 0, stream>>>(x, W, h);
  src_dst_k<<<64, 256, 0, stream>>>(h, aw, src, dst);
  sort_k<<<4, 1024, 0, stream>>>(dst, dsort, perm);
  prefix_k<<<4, 1024, 0, stream>>>(h, dsort, perm, P, S);
  out_k<<<64, 256, 0, stream>>>(src, dsort, P, S, out);
}

// Round 3
// 87.010 us; speedup vs baseline: 3.4032x; 2.7038x over previous
//
#include <hip/hip_runtime.h>

#define NN 4096
#define FIN 128
#define NHEAD 4
#define NHID 16
#define NCOL 64
#define SLOPE 0.2f
#define CHUNK 64
#define NCH 64      // NN / CHUNK
#define NCOLS 17    // 16 value cols + denominator col

__device__ __forceinline__ float lrelu(float v){ return v > 0.f ? v : SLOPE * v; }

// h = x @ W  (4096x128 @ 128x64)
__global__ __launch_bounds__(256) void gemm_h_k(const float* __restrict__ x,
                                                const float* __restrict__ W,
                                                float* __restrict__ h){
  __shared__ float wl[FIN][NCOL];   // 32 KB
  __shared__ float xl[16][FIN];     // 8 KB
  int t = threadIdx.x;
  for (int k = t; k < FIN * NCOL; k += 256) wl[k >> 6][k & 63] = W[k];
  int row0 = blockIdx.x * 16;
  for (int k = t; k < 16 * FIN; k += 256) xl[k >> 7][k & 127] = x[row0 * FIN + k];
  __syncthreads();
  int col = t & 63;
  int rb  = t >> 6;
  #pragma unroll
  for (int rr = 0; rr < 4; ++rr){
    int r = rb * 4 + rr;
    float acc = 0.f;
    #pragma unroll
    for (int d = 0; d < FIN; ++d) acc = fmaf(xl[r][d], wl[d][col], acc);
    h[(row0 + r) * NCOL + col] = acc;
  }
}

// src[h][n], dst[h][n]
__global__ __launch_bounds__(256) void src_dst_k(const float* __restrict__ h,
                                                 const float* __restrict__ aw,
                                                 float* __restrict__ src,
                                                 float* __restrict__ dst){
  int idx = blockIdx.x * 256 + threadIdx.x;   // n*4 + head
  int n = idx >> 2, hd = idx & 3;
  const float* hp = h + n * NCOL + hd * NHID;
  float s = 0.f, d = 0.f;
  #pragma unroll
  for (int f = 0; f < NHID; ++f){
    float v = hp[f];
    s = fmaf(v, aw[f], s);
    d = fmaf(v, aw[NHID + f], d);
  }
  src[hd * NN + n] = s;
  dst[hd * NN + n] = d;
}

// per-head ascending bitonic sort of dst, carrying original index
__global__ __launch_bounds__(1024) void sort_k(const float* __restrict__ dst,
                                               float* __restrict__ dsort,
                                               int* __restrict__ perm){
  int hd = blockIdx.x;
  __shared__ float v[NN];
  __shared__ int  ix[NN];
  int t = threadIdx.x;
  for (int k = t; k < NN; k += 1024){ v[k] = dst[hd * NN + k]; ix[k] = k; }
  __syncthreads();
  for (int kk = 2; kk <= NN; kk <<= 1){
    for (int j = kk >> 1; j > 0; j >>= 1){
      for (int q = t; q < NN / 2; q += 1024){
        int i = ((q & ~(j - 1)) << 1) | (q & (j - 1));
        int p = i | j;
        bool up = ((i & kk) == 0);
        float a = v[i], b = v[p];
        bool sw = up ? (a > b) : (a < b);
        if (sw){
          v[i] = b; v[p] = a;
          int tmp = ix[i]; ix[i] = ix[p]; ix[p] = tmp;
        }
      }
      __syncthreads();
    }
  }
  for (int k = t; k < NN; k += 1024){
    dsort[hd * NN + k] = v[k];
    perm[hd * NN + k]  = ix[k];
  }
}

// Per-(head, chunk) local scans.
// PL[(hd*17+c)*NN + k] = exclusive prefix of e^{0.2 d} * v_c within chunk
// SL[(hd*17+c)*NN + k] = inclusive suffix of e^{d} * v_c within chunk
// ctP/ctS[ch*68 + hd*17 + c] = chunk totals (transposed for scanB coalescing)
__global__ __launch_bounds__(256) void scanA_k(const float* __restrict__ h,
                                               const float* __restrict__ dsort,
                                               const int* __restrict__ perm,
                                               float* __restrict__ PL,
                                               float* __restrict__ SL,
                                               float* __restrict__ ctP,
                                               float* __restrict__ ctS){
  int ch = blockIdx.x;   // 64
  int hd = blockIdx.y;   // 4
  int t = threadIdx.x;
  int base = ch * CHUNK;
  __shared__ float e02[CHUNK], e1[CHUNK];
  __shared__ float hl[CHUNK][NCOLS];
  __shared__ float PLs[CHUNK][NCOLS], SLs[CHUNK][NCOLS];
  const float* ds = dsort + hd * NN;
  const int*   pm = perm + hd * NN;
  if (t < CHUNK){
    float d = ds[base + t];
    e02[t] = __expf(0.2f * d);
    e1[t]  = __expf(d);
    hl[t][16] = 1.0f;
  }
  {
    int col = t & 15, r0 = t >> 4;   // 16 rows x 16 cols per pass
    #pragma unroll
    for (int it = 0; it < 4; ++it){
      int r = it * 16 + r0;
      hl[r][col] = h[pm[base + r] * NCOL + hd * NHID + col];
    }
  }
  __syncthreads();
  if (t < NCOLS){
    int col = t;
    float run = 0.f;
    #pragma unroll
    for (int r = 0; r < CHUNK; ++r){
      PLs[r][col] = run;
      run = fmaf(e02[r], hl[r][col], run);
    }
    ctP[ch * 68 + hd * 17 + col] = run;
  } else if (t >= 64 && t < 64 + NCOLS){
    int col = t - 64;
    float rs = 0.f;
    #pragma unroll
    for (int r = CHUNK - 1; r >= 0; --r){
      rs = fmaf(e1[r], hl[r][col], rs);
      SLs[r][col] = rs;
    }
    ctS[ch * 68 + hd * 17 + col] = rs;
  }
  __syncthreads();
  for (int idx = t; idx < NCOLS * CHUNK; idx += 256){
    int col = idx >> 6, r = idx & 63;
    PL[(hd * 17 + col) * NN + base + r] = PLs[r][col];
    SL[(hd * 17 + col) * NN + base + r] = SLs[r][col];
  }
}

// in-place scan of chunk totals: ctP -> exclusive prefix offsets (+ grand total Ptot),
// ctS -> exclusive (from the right) suffix offsets
__global__ __launch_bounds__(256) void scanB_k(float* __restrict__ ctP,
                                               float* __restrict__ ctS,
                                               float* __restrict__ Ptot){
  int t = threadIdx.x;
  if (t < 68){
    float run = 0.f;
    #pragma unroll 8
    for (int c = 0; c < NCH; ++c){
      float v = ctP[c * 68 + t];
      ctP[c * 68 + t] = run;
      run += v;
    }
    Ptot[t] = run;
  } else if (t >= 128 && t < 196){
    int tt = t - 128;
    float rs = 0.f;
    #pragma unroll 8
    for (int c = NCH - 1; c >= 0; --c){
      float v = ctS[c * 68 + tt];
      ctS[c * 68 + tt] = rs;
      rs += v;
    }
  }
}

// per (i, head): binary search kink, two-level combine
__global__ __launch_bounds__(256) void out_k(const float* __restrict__ src,
                                             const float* __restrict__ dsort,
                                             const float* __restrict__ PL,
                                             const float* __restrict__ SL,
                                             const float* __restrict__ ctP,
                                             const float* __restrict__ ctS,
                                             const float* __restrict__ Ptot,
                                             float* __restrict__ out){
  int idx = blockIdx.x * 256 + threadIdx.x;  // 16384 = NN*NHEAD
  int i = idx >> 2, hd = idx & 3;
  float s = src[hd * NN + i];
  const float* ds = dsort + hd * NN;
  float tthr = -s;
  int lo = 0, hi = NN;
  while (lo < hi){
    int mid = (lo + hi) >> 1;
    if (ds[mid] < tthr) lo = mid + 1; else hi = mid;
  }
  int k = lo;                                 // ranks < k are in the 0.2-branch
  float* op = out + i * NCOL + hd * NHID;
  if (k == NN){
    const float* Pt = Ptot + hd * 17;
    float inv = 1.0f / Pt[16];
    #pragma unroll
    for (int f = 0; f < 16; ++f) op[f] = Pt[f] * inv;
  } else {
    float m = lrelu(s + ds[NN - 1]);
    float alpha = __expf(0.2f * s - m);
    float beta  = __expf(s - m);
    int ch = k >> 6;
    const float* PLp = PL + (hd * 17) * NN + k;
    const float* SLp = SL + (hd * 17) * NN + k;
    const float* oP  = ctP + ch * 68 + hd * 17;
    const float* oS  = ctS + ch * 68 + hd * 17;
    float den = alpha * (PLp[16 * NN] + oP[16]) + beta * (SLp[16 * NN] + oS[16]);
    float inv = 1.0f / den;
    #pragma unroll
    for (int f = 0; f < 16; ++f){
      float num = alpha * (PLp[f * NN] + oP[f]) + beta * (SLp[f * NN] + oS[f]);
      op[f] = num * inv;
    }
  }
}

extern "C" void kernel_launch(void* const* d_in, const int* in_sizes, int n_in,
                              void* d_out, int out_size, void* d_ws, size_t ws_size,
                              hipStream_t stream){
  const float* x  = (const float*)d_in[0];
  // d_in[1] = adj : UNUSED by the reference (no masking) — never read it.
  const float* W  = (const float*)d_in[2];
  const float* aw = (const float*)d_in[3];
  float* out = (float*)d_out;
  float* ws  = (float*)d_ws;

  float* h     = ws;                  // 262144
  float* src   = ws + 262144;         // 16384
  float* dst   = ws + 278528;         // 16384
  float* dsort = ws + 294912;         // 16384
  int*   perm  = (int*)(ws + 311296); // 16384
  float* PL    = ws + 327680;         // 278528
  float* SL    = ws + 606208;         // 278528
  float* ctP   = ws + 884736;         // 4352
  float* ctS   = ws + 889088;         // 4352
  float* Ptot  = ws + 893440;         // 68
  // total 893508 floats = 3.57 MB

  gemm_h_k<<<256, 256, 0, stream>>>(x, W, h);
  src_dst_k<<<64, 256, 0, stream>>>(h, aw, src, dst);
  sort_k<<<4, 1024, 0, stream>>>(dst, dsort, perm);
  scanA_k<<<dim3(NCH, NHEAD), 256, 0, stream>>>(h, dsort, perm, PL, SL, ctP, ctS);
  scanB_k<<<1, 256, 0, stream>>>(ctP, ctS, Ptot);
  out_k<<<64, 256, 0, stream>>>(src, dsort, PL, SL, ctP, ctS, Ptot, out);
}

// Round 4
// 58.807 us; speedup vs baseline: 5.0353x; 1.4796x over previous
//
#include <hip/hip_runtime.h>

#define NN 4096
#define FIN 128
#define NHEAD 4
#define NHID 16
#define NCOL 64
#define SLOPE 0.2f
#define CHUNK 64
#define NCH 64      // NN / CHUNK
#define NCOLS 17    // 16 value cols + denominator col

__device__ __forceinline__ float lrelu(float v){ return v > 0.f ? v : SLOPE * v; }

// h = x @ W (4096x128 @ 128x64), fused src/dst epilogue
__global__ __launch_bounds__(256) void gemm_h_k(const float* __restrict__ x,
                                                const float* __restrict__ W,
                                                const float* __restrict__ aw,
                                                float* __restrict__ h,
                                                float* __restrict__ src,
                                                float* __restrict__ dst){
  __shared__ float wl[FIN][NCOL];   // 32 KB
  __shared__ float xl[16][FIN];     // 8 KB
  __shared__ float hs[16][NCOL + 1]; // pad -> 2-way max on epilogue reads
  int t = threadIdx.x;
  for (int k = t; k < FIN * NCOL; k += 256) wl[k >> 6][k & 63] = W[k];
  int row0 = blockIdx.x * 16;
  for (int k = t; k < 16 * FIN; k += 256) xl[k >> 7][k & 127] = x[row0 * FIN + k];
  __syncthreads();
  int col = t & 63;
  int rb  = t >> 6;
  #pragma unroll
  for (int rr = 0; rr < 4; ++rr){
    int r = rb * 4 + rr;
    float acc = 0.f;
    #pragma unroll
    for (int d = 0; d < FIN; ++d) acc = fmaf(xl[r][d], wl[d][col], acc);
    h[(row0 + r) * NCOL + col] = acc;
    hs[r][col] = acc;
  }
  __syncthreads();
  if (t < 64){
    int r = t >> 2, hd = t & 3;
    float s = 0.f, d = 0.f;
    #pragma unroll
    for (int f = 0; f < NHID; ++f){
      float v = hs[r][hd * NHID + f];
      s = fmaf(v, aw[f], s);
      d = fmaf(v, aw[NHID + f], d);
    }
    src[hd * NN + row0 + r] = s;
    dst[hd * NN + row0 + r] = d;
  }
}

// partial ranks: count keys (u64 lexicographic) less than mine over a j-segment
__global__ __launch_bounds__(256) void rank_k(const float* __restrict__ dst,
                                              int* __restrict__ rankpart){
  int iseg = blockIdx.x;  // 16
  int hd   = blockIdx.y;  // 4
  int jseg = blockIdx.z;  // 4
  __shared__ unsigned long long keys[1024];   // 8 KB
  int t = threadIdx.x;
  const float* dp = dst + hd * NN;
  for (int k = t; k < 1024; k += 256){
    int j = jseg * 1024 + k;
    unsigned int b = __float_as_uint(dp[j]);
    b ^= (b & 0x80000000u) ? 0xFFFFFFFFu : 0x80000000u;
    keys[k] = ((unsigned long long)b << 32) | (unsigned int)j;
  }
  __syncthreads();
  int i = iseg * 256 + t;
  unsigned int bi = __float_as_uint(dp[i]);
  bi ^= (bi & 0x80000000u) ? 0xFFFFFFFFu : 0x80000000u;
  unsigned long long my = ((unsigned long long)bi << 32) | (unsigned int)i;
  int cnt = 0;
  #pragma unroll 8
  for (int k = 0; k < 1024; ++k) cnt += (keys[k] < my) ? 1 : 0;
  rankpart[(jseg * NHEAD + hd) * NN + i] = cnt;
}

// sum partials -> unique rank; scatter value+index into sorted order
__global__ __launch_bounds__(256) void scatter_k(const float* __restrict__ dst,
                                                 const int* __restrict__ rankpart,
                                                 float* __restrict__ dsort,
                                                 int* __restrict__ perm){
  int idx = blockIdx.x * 256 + threadIdx.x;  // hd*NN + i
  int hd = idx >> 12, i = idx & (NN - 1);
  int r = rankpart[(0 * NHEAD + hd) * NN + i]
        + rankpart[(1 * NHEAD + hd) * NN + i]
        + rankpart[(2 * NHEAD + hd) * NN + i]
        + rankpart[(3 * NHEAD + hd) * NN + i];
  dsort[hd * NN + r] = dst[hd * NN + i];
  perm[hd * NN + r]  = i;
}

// Per-(head, chunk) local scans.
// PL[(hd*17+c)*NN + k] = exclusive prefix of e^{0.2 d} * v_c within chunk
// SL[(hd*17+c)*NN + k] = inclusive suffix of e^{d} * v_c within chunk
// ctP/ctS[ch*68 + hd*17 + c] = chunk totals (transposed for scanB coalescing)
__global__ __launch_bounds__(256) void scanA_k(const float* __restrict__ h,
                                               const float* __restrict__ dsort,
                                               const int* __restrict__ perm,
                                               float* __restrict__ PL,
                                               float* __restrict__ SL,
                                               float* __restrict__ ctP,
                                               float* __restrict__ ctS){
  int ch = blockIdx.x;   // 64
  int hd = blockIdx.y;   // 4
  int t = threadIdx.x;
  int base = ch * CHUNK;
  __shared__ float e02[CHUNK], e1[CHUNK];
  __shared__ float hl[CHUNK][NCOLS];
  __shared__ float PLs[CHUNK][NCOLS], SLs[CHUNK][NCOLS];
  const float* ds = dsort + hd * NN;
  const int*   pm = perm + hd * NN;
  if (t < CHUNK){
    float d = ds[base + t];
    e02[t] = __expf(0.2f * d);
    e1[t]  = __expf(d);
    hl[t][16] = 1.0f;
  }
  {
    int col = t & 15, r0 = t >> 4;   // 16 rows x 16 cols per pass
    #pragma unroll
    for (int it = 0; it < 4; ++it){
      int r = it * 16 + r0;
      hl[r][col] = h[pm[base + r] * NCOL + hd * NHID + col];
    }
  }
  __syncthreads();
  if (t < NCOLS){
    int col = t;
    float run = 0.f;
    #pragma unroll
    for (int r = 0; r < CHUNK; ++r){
      PLs[r][col] = run;
      run = fmaf(e02[r], hl[r][col], run);
    }
    ctP[ch * 68 + hd * 17 + col] = run;
  } else if (t >= 64 && t < 64 + NCOLS){
    int col = t - 64;
    float rs = 0.f;
    #pragma unroll
    for (int r = CHUNK - 1; r >= 0; --r){
      rs = fmaf(e1[r], hl[r][col], rs);
      SLs[r][col] = rs;
    }
    ctS[ch * 68 + hd * 17 + col] = rs;
  }
  __syncthreads();
  for (int idx = t; idx < NCOLS * CHUNK; idx += 256){
    int col = idx >> 6, r = idx & 63;
    PL[(hd * 17 + col) * NN + base + r] = PLs[r][col];
    SL[(hd * 17 + col) * NN + base + r] = SLs[r][col];
  }
}

// in-place scan of chunk totals: ctP -> exclusive prefix offsets (+ grand total Ptot),
// ctS -> exclusive (from the right) suffix offsets
__global__ __launch_bounds__(256) void scanB_k(float* __restrict__ ctP,
                                               float* __restrict__ ctS,
                                               float* __restrict__ Ptot){
  int t = threadIdx.x;
  if (t < 68){
    float run = 0.f;
    #pragma unroll 8
    for (int c = 0; c < NCH; ++c){
      float v = ctP[c * 68 + t];
      ctP[c * 68 + t] = run;
      run += v;
    }
    Ptot[t] = run;
  } else if (t >= 128 && t < 196){
    int tt = t - 128;
    float rs = 0.f;
    #pragma unroll 8
    for (int c = NCH - 1; c >= 0; --c){
      float v = ctS[c * 68 + tt];
      ctS[c * 68 + tt] = rs;
      rs += v;
    }
  }
}

// per (i, head): binary search kink, two-level combine
__global__ __launch_bounds__(256) void out_k(const float* __restrict__ src,
                                             const float* __restrict__ dsort,
                                             const float* __restrict__ PL,
                                             const float* __restrict__ SL,
                                             const float* __restrict__ ctP,
                                             const float* __restrict__ ctS,
                                             const float* __restrict__ Ptot,
                                             float* __restrict__ out){
  int idx = blockIdx.x * 256 + threadIdx.x;  // 16384 = NN*NHEAD
  int i = idx >> 2, hd = idx & 3;
  float s = src[hd * NN + i];
  const float* ds = dsort + hd * NN;
  float tthr = -s;
  int lo = 0, hi = NN;
  while (lo < hi){
    int mid = (lo + hi) >> 1;
    if (ds[mid] < tthr) lo = mid + 1; else hi = mid;
  }
  int k = lo;                                 // ranks < k are in the 0.2-branch
  float* op = out + i * NCOL + hd * NHID;
  if (k == NN){
    const float* Pt = Ptot + hd * 17;
    float inv = 1.0f / Pt[16];
    #pragma unroll
    for (int f = 0; f < 16; ++f) op[f] = Pt[f] * inv;
  } else {
    float m = lrelu(s + ds[NN - 1]);
    float alpha = __expf(0.2f * s - m);
    float beta  = __expf(s - m);
    int ch = k >> 6;
    const float* PLp = PL + (hd * 17) * NN + k;
    const float* SLp = SL + (hd * 17) * NN + k;
    const float* oP  = ctP + ch * 68 + hd * 17;
    const float* oS  = ctS + ch * 68 + hd * 17;
    float den = alpha * (PLp[16 * NN] + oP[16]) + beta * (SLp[16 * NN] + oS[16]);
    float inv = 1.0f / den;
    #pragma unroll
    for (int f = 0; f < 16; ++f){
      float num = alpha * (PLp[f * NN] + oP[f]) + beta * (SLp[f * NN] + oS[f]);
      op[f] = num * inv;
    }
  }
}

extern "C" void kernel_launch(void* const* d_in, const int* in_sizes, int n_in,
                              void* d_out, int out_size, void* d_ws, size_t ws_size,
                              hipStream_t stream){
  const float* x  = (const float*)d_in[0];
  // d_in[1] = adj : UNUSED by the reference (no masking) — never read it.
  const float* W  = (const float*)d_in[2];
  const float* aw = (const float*)d_in[3];
  float* out = (float*)d_out;
  float* ws  = (float*)d_ws;

  float* h        = ws;                   // 262144
  float* src      = ws + 262144;          // 16384
  float* dst      = ws + 278528;          // 16384
  float* dsort    = ws + 294912;          // 16384
  int*   perm     = (int*)(ws + 311296);  // 16384
  float* PL       = ws + 327680;          // 278528
  float* SL       = ws + 606208;          // 278528
  float* ctP      = ws + 884736;          // 4352
  float* ctS      = ws + 889088;          // 4352
  float* Ptot     = ws + 893440;          // 68 (+pad)
  int*   rankpart = (int*)(ws + 893568);  // 4*4*4096 = 65536
  // total 959104 floats = 3.84 MB

  gemm_h_k<<<256, 256, 0, stream>>>(x, W, aw, h, src, dst);
  rank_k<<<dim3(16, NHEAD, 4), 256, 0, stream>>>(dst, rankpart);
  scatter_k<<<64, 256, 0, stream>>>(dst, rankpart, dsort, perm);
  scanA_k<<<dim3(NCH, NHEAD), 256, 0, stream>>>(h, dsort, perm, PL, SL, ctP, ctS);
  scanB_k<<<1, 256, 0, stream>>>(ctP, ctS, Ptot);
  out_k<<<64, 256, 0, stream>>>(src, dsort, PL, SL, ctP, ctS, Ptot, out);
}